// Round 23
// baseline (27.329 us; speedup 1.0000x reference)
//
#include <hip/hip_runtime.h>
#include <hip/hip_bf16.h>

#define IN_F   4096
#define OUT_F  11008
#define BATCH  32
#define NTILE  16
#define GRID_N (OUT_F / NTILE)    // 688

typedef __attribute__((ext_vector_type(8))) short  bf16x8;
typedef __attribute__((ext_vector_type(4))) float  f32x4;
typedef __attribute__((ext_vector_type(4))) int    i32x4;
typedef __attribute__((ext_vector_type(4))) float  float4v;

static __device__ __constant__ float NF4_LEVELS[16] = {
    -1.0f, -0.6961928009986877f, -0.5250730514526367f, -0.39491748809814453f,
    -0.28444138169288635f, -0.18477343022823334f, -0.09105003625154495f, 0.0f,
    0.07958029955625534f, 0.16093020141124725f, 0.24611230194568634f,
    0.33791524171829224f, 0.44070982933044434f, 0.5626170039176941f,
    0.7229568362236023f, 1.0f};

// ---------------------------------------------------------------------------
// Prelude (64 blocks): A-fragment streams in MFMA order:
//   frag[st][kb][lane] (16B) = x[st*16+(lane&15)][kb*32+(lane>>4)*8..+8) bf16
// ---------------------------------------------------------------------------
__global__ void prelude_kernel(const float* __restrict__ x,
                               unsigned short* __restrict__ frag) {
    int T  = blockIdx.x * 256 + threadIdx.x;
    int st = T >> 13;
    int kb = (T >> 6) & 127;
    int l  = T & 63;
    int row = st * 16 + (l & 15);
    int k0  = kb * 32 + (l >> 4) * 8;
    const float* src = x + (size_t)row * IN_F + k0;
    unsigned w[4];
    #pragma unroll
    for (int e = 0; e < 4; ++e) {
        unsigned lo = __builtin_bit_cast(unsigned short, __float2bfloat16(src[2 * e]));
        unsigned hi = __builtin_bit_cast(unsigned short, __float2bfloat16(src[2 * e + 1]));
        w[e] = lo | (hi << 16);
    }
    i32x4 v = { (int)w[0], (int)w[1], (int)w[2], (int)w[3] };
    *reinterpret_cast<i32x4*>(frag + ((size_t)st * 8192 + kb * 64 + l) * 8) = v;
}

// ---------------------------------------------------------------------------
// Main: grid 688, 256 thr (4 waves). R20 structure (DMA staging, best
// measured 26.2us) + ISSUE-ORDER SWAP (this round's single variable):
// A-fragment loads issue BEFORE stage(u+1) DMAs inside each unit body.
// vmcnt retires OLDEST-FIRST (m135): in R20 the stage DMAs were oldest, so
// the first MFMA's counted A-wait had to retire 4 HBM-latency DMAs (~900cyc)
// before the L2-hit A-loads (~200cyc) — up to ~700cyc exposed per unit.
// With A-loads oldest, the mid-unit wait drains only the cheap A-loads and
// the stage DMAs keep a FULL unit of compute in flight, drained only at the
// next boundary vmcnt(0). sched_barrier(0) pins the issue order.
//
// Block = 16 out-rows x full K=4096; wave w owns k [w*1024,+1024) as
// 8 units of 128 k, double-buffered (2 x 4KB raw-code bufs per wave).
// Staging a unit = 4 fire-and-forget global_load_lds wave-instrs (1KB each):
//   - LDS dest LINEAR (uniform base + lane*16): [row][granule] raw int32
//   - bank swizzle on the GLOBAL SOURCE (rule #21): granule gq ^ (row&7) —
//     permutes 16B granules within the row's contiguous 256B; wave still
//     covers one contiguous 1KB (zero coalescing loss)
//   - reader: ds_read_b128 at col*64 + ((t*4+g)^(col&7))*4 -> 2 lanes/bank
//   - no compaction: tabu index = raw dword & 255
// Boundary per unit: s_waitcnt vmcnt(0) + sched_barrier(0). Zero block
// barriers in the K-loop; one final reduce barrier.
// ---------------------------------------------------------------------------
__global__ __launch_bounds__(256, 4) void nf4_gemm_kernel(
        const int* __restrict__ packed,
        const float* __restrict__ scales,
        const float* __restrict__ bias,
        const unsigned short* __restrict__ frag,
        float* __restrict__ out)
{
    __shared__ unsigned lds[9216];   // 1024 tabu (4x256) | 4 waves x 2048 dw

    const int tid  = threadIdx.x;
    const int wave = tid >> 6;
    const int lane = tid & 63;
    const int col  = lane & 15;
    const int g    = lane >> 4;

    const int n0 = blockIdx.x * NTILE;

    // ---- wave-private tabu (in-wave DS ordering; no barrier) ----
    #pragma unroll
    for (int q = 0; q < 4; ++q) {
        int e = q * 64 + lane;
        unsigned lo = __builtin_bit_cast(unsigned short, __float2bfloat16(NF4_LEVELS[e & 15]));
        unsigned hi = __builtin_bit_cast(unsigned short, __float2bfloat16(NF4_LEVELS[(e >> 4) & 15]));
        lds[wave * 256 + e] = lo | (hi << 16);
    }

    // ---- scales in registers: row n0+col, groups wave*8 .. +8 ----
    float scw[8];
    {
        const float* sp = scales + (size_t)(n0 + col) * 32 + wave * 8;
        float4v sv0 = *reinterpret_cast<const float4v*>(sp);
        float4v sv1 = *reinterpret_cast<const float4v*>(sp + 4);
        scw[0]=sv0.x; scw[1]=sv0.y; scw[2]=sv0.z; scw[3]=sv0.w;
        scw[4]=sv1.x; scw[5]=sv1.y; scw[6]=sv1.z; scw[7]=sv1.w;
    }

    unsigned* cbase = &lds[1024 + wave * 2048];   // this wave's 2 x 1024 dw

    // DMA-stage unit u (128 k x 16 rows = 4KB) into buf (u&1).
    // instr q covers rows 4q..4q+3; lane: rl = 4q+(lane>>4), gq = lane&15;
    // source granule = gq ^ (rl&7)  (16B-granule XOR, coalescing-preserving)
    #define STAGE(u)                                                           \
        _Pragma("unroll")                                                      \
        for (int q = 0; q < 4; ++q) {                                          \
            int rl = q * 4 + (lane >> 4);                                      \
            int gq = lane & 15;                                                \
            const int* srcp = packed                                           \
                + (size_t)(n0 + rl) * (IN_F / 2)                               \
                + wave * 512 + (u) * 64 + (gq ^ (rl & 7)) * 4;                 \
            __builtin_amdgcn_global_load_lds(                                  \
                (const __attribute__((address_space(1))) unsigned int*)srcp,   \
                (__attribute__((address_space(3))) unsigned int*)              \
                    (cbase + ((u) & 1) * 1024 + q * 256),                      \
                16, 0, 0);                                                     \
        }

    f32x4 acc0 = (f32x4){0.f,0.f,0.f,0.f};   // batch 0-15
    f32x4 acc1 = (f32x4){0.f,0.f,0.f,0.f};   // batch 16-31

    const unsigned short* f0 = frag;
    const unsigned short* f1 = frag + 65536;

    STAGE(0)

    #pragma unroll
    for (int u = 0; u < 8; ++u) {
        // boundary: drain stage(u); block ds/MFMA hoisting above the wait
        asm volatile("s_waitcnt vmcnt(0)" ::: "memory");
        __builtin_amdgcn_sched_barrier(0);

        // A fragments FIRST (oldest VMEM of this unit -> their mid-unit
        // counted wait no longer forces the stage DMAs to retire)
        bf16x8 A0[4], A1[4];
        #pragma unroll
        for (int t = 0; t < 4; ++t) {
            int kb = wave * 32 + u * 4 + t;
            A0[t] = *reinterpret_cast<const bf16x8*>(f0 + ((size_t)kb * 64 + lane) * 8);
            A1[t] = *reinterpret_cast<const bf16x8*>(f1 + ((size_t)kb * 64 + lane) * 8);
        }
        __builtin_amdgcn_sched_barrier(0);       // pin: A-loads BEFORE DMAs

        if (u + 1 < 8) { STAGE(u + 1) }          // newest: full unit of flight

        f32x4 t0 = (f32x4){0.f,0.f,0.f,0.f};
        f32x4 t1 = (f32x4){0.f,0.f,0.f,0.f};
        #pragma unroll
        for (int t = 0; t < 4; ++t) {
            // raw codes: b128 at swizzled granule (2 lanes/bank, free)
            i32x4 cd = *reinterpret_cast<const i32x4*>(
                &cbase[(u & 1) * 1024 + col * 64 + (((t * 4 + g) ^ (col & 7)) * 4)]);
            i32x4 bu;                            // bfrag once, both halves
            bu[0] = (int)lds[wave * 256 + ((unsigned)cd[0] & 255u)];
            bu[1] = (int)lds[wave * 256 + ((unsigned)cd[1] & 255u)];
            bu[2] = (int)lds[wave * 256 + ((unsigned)cd[2] & 255u)];
            bu[3] = (int)lds[wave * 256 + ((unsigned)cd[3] & 255u)];
            bf16x8 bf = __builtin_bit_cast(bf16x8, bu);
            t0 = __builtin_amdgcn_mfma_f32_16x16x32_bf16(A0[t], bf, t0, 0, 0, 0);
            t1 = __builtin_amdgcn_mfma_f32_16x16x32_bf16(A1[t], bf, t1, 0, 0, 0);
        }
        const float sc = scw[u];                 // unit == one scale group
        #pragma unroll
        for (int j = 0; j < 4; ++j) {
            acc0[j] = fmaf(sc, t0[j], acc0[j]);
            acc1[j] = fmaf(sc, t1[j], acc1[j]);
        }
    }

    // ---- epilogue: red aliases wave's own buffers (reads done; stage(7)
    // drained at the u=7 boundary) ----
    float* red = (float*)cbase;
    #pragma unroll
    for (int j = 0; j < 4; ++j) {
        red[(0 * 4 + j) * 64 + g * 16 + col] = acc0[j];
        red[(1 * 4 + j) * 64 + g * 16 + col] = acc1[j];
    }
    __syncthreads();             // the ONE barrier

    #pragma unroll
    for (int p = 0; p < 2; ++p) {
        int idx = p * 256 + tid;             // [0,512)
        int b   = idx >> 4;                  // batch row
        int c   = idx & 15;                  // out-feature local
        int h   = b >> 4;
        int r   = b & 15;
        int j   = r & 3;
        int g2  = r >> 2;
        int slot = (h * 4 + j) * 64 + g2 * 16 + c;
        const float* rbase = (const float*)&lds[1024];
        float s = rbase[slot] + rbase[2048 + slot]
                + rbase[4096 + slot] + rbase[6144 + slot];
        out[(size_t)b * OUT_F + n0 + c] = s + bias[n0 + c];
    }
}

// ---------------------------------------------------------------------------
extern "C" void kernel_launch(void* const* d_in, const int* in_sizes, int n_in,
                              void* d_out, int out_size, void* d_ws, size_t ws_size,
                              hipStream_t stream) {
    const float* x      = (const float*)d_in[0];
    const int*   packed = (const int*)d_in[1];
    const float* scales = (const float*)d_in[2];
    const float* bias   = (const float*)d_in[3];
    float* out = (float*)d_out;

    unsigned short* frag = (unsigned short*)d_ws;   // 256 KB

    prelude_kernel<<<64, 256, 0, stream>>>(x, frag);
    nf4_gemm_kernel<<<GRID_N, 256, 0, stream>>>(packed, scales, bias, frag, out);
}

// Round 24
// 26.570 us; speedup vs baseline: 1.0286x; 1.0286x over previous
//
#include <hip/hip_runtime.h>
#include <hip/hip_bf16.h>

#define IN_F   4096
#define OUT_F  11008
#define BATCH  32
#define NTILE  16
#define GRID_N (OUT_F / NTILE)    // 688

typedef __attribute__((ext_vector_type(8))) short  bf16x8;
typedef __attribute__((ext_vector_type(4))) float  f32x4;
typedef __attribute__((ext_vector_type(4))) int    i32x4;
typedef __attribute__((ext_vector_type(4))) float  float4v;

static __device__ __constant__ float NF4_LEVELS[16] = {
    -1.0f, -0.6961928009986877f, -0.5250730514526367f, -0.39491748809814453f,
    -0.28444138169288635f, -0.18477343022823334f, -0.09105003625154495f, 0.0f,
    0.07958029955625534f, 0.16093020141124725f, 0.24611230194568634f,
    0.33791524171829224f, 0.44070982933044434f, 0.5626170039176941f,
    0.7229568362236023f, 1.0f};

// ---------------------------------------------------------------------------
// Prelude (64 blocks): A-fragment streams in MFMA order:
//   frag[st][kb][lane] (16B) = x[st*16+(lane&15)][kb*32+(lane>>4)*8..+8) bf16
// ---------------------------------------------------------------------------
__global__ void prelude_kernel(const float* __restrict__ x,
                               unsigned short* __restrict__ frag) {
    int T  = blockIdx.x * 256 + threadIdx.x;
    int st = T >> 13;
    int kb = (T >> 6) & 127;
    int l  = T & 63;
    int row = st * 16 + (l & 15);
    int k0  = kb * 32 + (l >> 4) * 8;
    const float* src = x + (size_t)row * IN_F + k0;
    unsigned w[4];
    #pragma unroll
    for (int e = 0; e < 4; ++e) {
        unsigned lo = __builtin_bit_cast(unsigned short, __float2bfloat16(src[2 * e]));
        unsigned hi = __builtin_bit_cast(unsigned short, __float2bfloat16(src[2 * e + 1]));
        w[e] = lo | (hi << 16);
    }
    i32x4 v = { (int)w[0], (int)w[1], (int)w[2], (int)w[3] };
    *reinterpret_cast<i32x4*>(frag + ((size_t)st * 8192 + kb * 64 + l) * 8) = v;
}

// ---------------------------------------------------------------------------
// Main: grid 688, 256 thr (4 waves). [R20 — FINAL. Best measured of 24
// rounds: 26.2us (R22 repro: 26.7). Neighbors all measured worse:
// A-reg-prefetch (R21, 27.4: VGPR occupancy step), issue-order swap (R23,
// 27.3), bigger tiles / K-split / atomics / more barriers (R11-R18,
// 28.6-35.4). The two real mechanisms of the session: barrier-free
// wave-private staging (44.7->28.0) and global_load_lds DMA staging
// (28.0->26.2).]
//
// Block = 16 out-rows x full K=4096; wave w owns k [w*1024,+1024) as
// 8 units of 128 k, double-buffered (2 x 4KB raw-code bufs per wave).
// Staging a unit = 4 fire-and-forget global_load_lds wave-instrs (1KB each):
//   - LDS dest LINEAR (uniform base + lane*16): [row][granule] raw int32
//   - bank swizzle applied on the GLOBAL SOURCE (rule #21): lane's source
//     granule = gq ^ (row&7) — permutes 16B granules within the row's
//     contiguous 256B -> wave still covers one contiguous 1KB (zero
//     coalescing loss). LDS[row][gq] holds global granule gq^(row&7).
//   - reader (lane col,g; k-step t): ds_read_b128 at
//     col*64 + ((t*4+g)^(col&7))*4 dwords -> 2 lanes/bank (free, m136)
//   - no compaction: tabu index = raw dword & 255 (byte extract folds into
//     LDS address math). No staging VGPRs, no ds_writes.
// Boundary per unit: s_waitcnt vmcnt(0) + sched_barrier(0) (memory clobber
// also stops cross-unit ds_read motion — DMA LDS-writes are compiler-
// invisible). stage(u+1) issues right AFTER the wait -> flies under
// compute(u); mid-unit A-consumption (L2-hit) implicitly overlaps the DMA
// flight via vmcnt oldest-first. ZERO block barriers in the K-loop; one
// final reduce barrier (red aliases wave's own dead buffers).
// ---------------------------------------------------------------------------
__global__ __launch_bounds__(256, 4) void nf4_gemm_kernel(
        const int* __restrict__ packed,
        const float* __restrict__ scales,
        const float* __restrict__ bias,
        const unsigned short* __restrict__ frag,
        float* __restrict__ out)
{
    __shared__ unsigned lds[9216];   // 1024 tabu (4x256) | 4 waves x 2048 dw

    const int tid  = threadIdx.x;
    const int wave = tid >> 6;
    const int lane = tid & 63;
    const int col  = lane & 15;
    const int g    = lane >> 4;

    const int n0 = blockIdx.x * NTILE;

    // ---- wave-private tabu (in-wave DS ordering; no barrier) ----
    #pragma unroll
    for (int q = 0; q < 4; ++q) {
        int e = q * 64 + lane;
        unsigned lo = __builtin_bit_cast(unsigned short, __float2bfloat16(NF4_LEVELS[e & 15]));
        unsigned hi = __builtin_bit_cast(unsigned short, __float2bfloat16(NF4_LEVELS[(e >> 4) & 15]));
        lds[wave * 256 + e] = lo | (hi << 16);
    }

    // ---- scales in registers: row n0+col, groups wave*8 .. +8 ----
    float scw[8];
    {
        const float* sp = scales + (size_t)(n0 + col) * 32 + wave * 8;
        float4v sv0 = *reinterpret_cast<const float4v*>(sp);
        float4v sv1 = *reinterpret_cast<const float4v*>(sp + 4);
        scw[0]=sv0.x; scw[1]=sv0.y; scw[2]=sv0.z; scw[3]=sv0.w;
        scw[4]=sv1.x; scw[5]=sv1.y; scw[6]=sv1.z; scw[7]=sv1.w;
    }

    unsigned* cbase = &lds[1024 + wave * 2048];   // this wave's 2 x 1024 dw

    // DMA-stage unit u (128 k x 16 rows = 4KB) into buf (u&1).
    // instr q covers rows 4q..4q+3; lane: rl = 4q+(lane>>4), gq = lane&15;
    // source granule = gq ^ (rl&7)  (16B-granule XOR, coalescing-preserving)
    #define STAGE(u)                                                           \
        _Pragma("unroll")                                                      \
        for (int q = 0; q < 4; ++q) {                                          \
            int rl = q * 4 + (lane >> 4);                                      \
            int gq = lane & 15;                                                \
            const int* srcp = packed                                           \
                + (size_t)(n0 + rl) * (IN_F / 2)                               \
                + wave * 512 + (u) * 64 + (gq ^ (rl & 7)) * 4;                 \
            __builtin_amdgcn_global_load_lds(                                  \
                (const __attribute__((address_space(1))) unsigned int*)srcp,   \
                (__attribute__((address_space(3))) unsigned int*)              \
                    (cbase + ((u) & 1) * 1024 + q * 256),                      \
                16, 0, 0);                                                     \
        }

    f32x4 acc0 = (f32x4){0.f,0.f,0.f,0.f};   // batch 0-15
    f32x4 acc1 = (f32x4){0.f,0.f,0.f,0.f};   // batch 16-31

    const unsigned short* f0 = frag;
    const unsigned short* f1 = frag + 65536;

    STAGE(0)

    #pragma unroll
    for (int u = 0; u < 8; ++u) {
        // boundary: drain stage(u) (and any spent A-loads); block ds hoisting
        asm volatile("s_waitcnt vmcnt(0)" ::: "memory");
        __builtin_amdgcn_sched_barrier(0);
        if (u + 1 < 8) { STAGE(u + 1) }          // flies under compute(u)

        // A fragments for this unit (8 x 1KB contiguous, L2-resident)
        bf16x8 A0[4], A1[4];
        #pragma unroll
        for (int t = 0; t < 4; ++t) {
            int kb = wave * 32 + u * 4 + t;
            A0[t] = *reinterpret_cast<const bf16x8*>(f0 + ((size_t)kb * 64 + lane) * 8);
            A1[t] = *reinterpret_cast<const bf16x8*>(f1 + ((size_t)kb * 64 + lane) * 8);
        }

        f32x4 t0 = (f32x4){0.f,0.f,0.f,0.f};
        f32x4 t1 = (f32x4){0.f,0.f,0.f,0.f};
        #pragma unroll
        for (int t = 0; t < 4; ++t) {
            // raw codes: b128 at swizzled granule (2 lanes/bank, free)
            i32x4 cd = *reinterpret_cast<const i32x4*>(
                &cbase[(u & 1) * 1024 + col * 64 + (((t * 4 + g) ^ (col & 7)) * 4)]);
            i32x4 bu;                            // bfrag once, both halves
            bu[0] = (int)lds[wave * 256 + ((unsigned)cd[0] & 255u)];
            bu[1] = (int)lds[wave * 256 + ((unsigned)cd[1] & 255u)];
            bu[2] = (int)lds[wave * 256 + ((unsigned)cd[2] & 255u)];
            bu[3] = (int)lds[wave * 256 + ((unsigned)cd[3] & 255u)];
            bf16x8 bf = __builtin_bit_cast(bf16x8, bu);
            t0 = __builtin_amdgcn_mfma_f32_16x16x32_bf16(A0[t], bf, t0, 0, 0, 0);
            t1 = __builtin_amdgcn_mfma_f32_16x16x32_bf16(A1[t], bf, t1, 0, 0, 0);
        }
        const float sc = scw[u];                 // unit == one scale group
        #pragma unroll
        for (int j = 0; j < 4; ++j) {
            acc0[j] = fmaf(sc, t0[j], acc0[j]);
            acc1[j] = fmaf(sc, t1[j], acc1[j]);
        }
    }

    // ---- epilogue: red aliases wave's own buffers (reads done, no DMA
    // outstanding: stage(7) drained at u=7 boundary) ----
    float* red = (float*)cbase;
    #pragma unroll
    for (int j = 0; j < 4; ++j) {
        red[(0 * 4 + j) * 64 + g * 16 + col] = acc0[j];
        red[(1 * 4 + j) * 64 + g * 16 + col] = acc1[j];
    }
    __syncthreads();             // the ONE barrier

    #pragma unroll
    for (int p = 0; p < 2; ++p) {
        int idx = p * 256 + tid;             // [0,512)
        int b   = idx >> 4;                  // batch row
        int c   = idx & 15;                  // out-feature local
        int h   = b >> 4;
        int r   = b & 15;
        int j   = r & 3;
        int g2  = r >> 2;
        int slot = (h * 4 + j) * 64 + g2 * 16 + c;
        const float* rbase = (const float*)&lds[1024];
        float s = rbase[slot] + rbase[2048 + slot]
                + rbase[4096 + slot] + rbase[6144 + slot];
        out[(size_t)b * OUT_F + n0 + c] = s + bias[n0 + c];
    }
}

// ---------------------------------------------------------------------------
extern "C" void kernel_launch(void* const* d_in, const int* in_sizes, int n_in,
                              void* d_out, int out_size, void* d_ws, size_t ws_size,
                              hipStream_t stream) {
    const float* x      = (const float*)d_in[0];
    const int*   packed = (const int*)d_in[1];
    const float* scales = (const float*)d_in[2];
    const float* bias   = (const float*)d_in[3];
    float* out = (float*)d_out;

    unsigned short* frag = (unsigned short*)d_ws;   // 256 KB

    prelude_kernel<<<64, 256, 0, stream>>>(x, frag);
    nf4_gemm_kernel<<<GRID_N, 256, 0, stream>>>(packed, scales, bias, frag, out);
}